// Round 1
// baseline (1333.239 us; speedup 1.0000x reference)
//
#include <hip/hip_runtime.h>
#include <hip/hip_bf16.h>

#define NFEAT 128

// ---------------------------------------------------------------------------
// GEMM: Y[nrows x COLS] = X[nrows x 128] @ W[128 x COLS]
// Block = 256 threads handles RB=16 rows. W staged in LDS (row-major,
// consecutive cols across lanes -> conflict-free b32 reads, 2 lanes/bank is
// free on gfx950). X rows staged in LDS, read as broadcast float4.
// ---------------------------------------------------------------------------
template <int COLS, int RB>
__global__ __launch_bounds__(256) void gemm_kernel(
    const float* __restrict__ X, const float* __restrict__ W,
    float* __restrict__ Y, int nrows) {
  constexpr int G = 256 / COLS;   // row groups per block
  constexpr int RPT = RB / G;     // rows per thread
  __shared__ __align__(16) float Ws[128 * COLS];
  __shared__ __align__(16) float xs[RB][128];

  const int tid = threadIdx.x;
  const int row0 = blockIdx.x * RB;

  // Stage W (L2-resident after first blocks)
  for (int i = tid * 4; i < 128 * COLS; i += 256 * 4) {
    *(float4*)&Ws[i] = *(const float4*)&W[i];
  }
  // Stage RB rows of X
  for (int i = tid * 4; i < RB * 128; i += 256 * 4) {
    int r = i >> 7, c = i & 127;
    int gr = row0 + r;
    float4 v = make_float4(0.f, 0.f, 0.f, 0.f);
    if (gr < nrows) v = *(const float4*)&X[(size_t)gr * 128 + c];
    *(float4*)&xs[r][c] = v;
  }
  __syncthreads();

  const int col = tid % COLS;
  const int rg = tid / COLS;

  float acc[RPT];
#pragma unroll
  for (int j = 0; j < RPT; j++) acc[j] = 0.f;

#pragma unroll 4
  for (int k = 0; k < 128; k += 4) {
    float w0 = Ws[(k + 0) * COLS + col];
    float w1 = Ws[(k + 1) * COLS + col];
    float w2 = Ws[(k + 2) * COLS + col];
    float w3 = Ws[(k + 3) * COLS + col];
#pragma unroll
    for (int j = 0; j < RPT; j++) {
      int r = rg + G * j;
      float4 xv = *(float4*)&xs[r][k];   // broadcast within wave -> free
      acc[j] += xv.x * w0 + xv.y * w1 + xv.z * w2 + xv.w * w3;
    }
  }

#pragma unroll
  for (int j = 0; j < RPT; j++) {
    int r = row0 + rg + G * j;
    if (r < nrows) Y[(size_t)r * COLS + col] = acc[j];
  }
}

// ---------------------------------------------------------------------------
// Scatter-add: agg[dst[e]][c] += Y[src[e]][c]   (C channels per edge)
// 128 (or 64) consecutive threads share one edge -> gather loads and atomics
// are fully coalesced across lanes.
// ---------------------------------------------------------------------------
template <int C>
__global__ __launch_bounds__(256) void scatter_add_kernel(
    const float* __restrict__ Y, const int* __restrict__ src,
    const int* __restrict__ dst, float* __restrict__ agg, int E) {
  int t = blockIdx.x * 256 + threadIdx.x;
  int e = t / C;
  int c = t % C;
  if (e >= E) return;
  int s = src[e];
  int d = dst[e];
  atomicAdd(&agg[(size_t)d * C + c], Y[(size_t)s * C + c]);
}

// h = relu(agg + b1), elementwise over N*128
__global__ __launch_bounds__(256) void relu_bias_kernel(
    const float* __restrict__ agg, const float* __restrict__ b,
    float* __restrict__ h, int n) {
  int t = blockIdx.x * 256 + threadIdx.x;
  if (t >= n) return;
  float v = agg[t] + b[t & (NFEAT - 1)];
  h[t] = v > 0.f ? v : 0.f;
}

// out[n][c] = b2[c]  (init before final scatter)
__global__ __launch_bounds__(256) void bias_init_kernel(
    const float* __restrict__ b, float* __restrict__ out, int n) {
  int t = blockIdx.x * 256 + threadIdx.x;
  if (t >= n) return;
  out[t] = b[t & 63];
}

extern "C" void kernel_launch(void* const* d_in, const int* in_sizes, int n_in,
                              void* d_out, int out_size, void* d_ws, size_t ws_size,
                              hipStream_t stream) {
  const float* x  = (const float*)d_in[0];
  const int* src  = (const int*)d_in[1];
  const int* dst  = (const int*)d_in[2];
  const float* W1 = (const float*)d_in[3];
  const float* b1 = (const float*)d_in[4];
  const float* W2 = (const float*)d_in[5];
  const float* b2 = (const float*)d_in[6];
  float* out = (float*)d_out;

  const int N = in_sizes[0] / NFEAT;   // 100000
  const int E = in_sizes[1];           // 1600000

  float* bufA = (float*)d_ws;                  // N*128 fp32
  float* bufB = bufA + (size_t)N * NFEAT;      // N*128 fp32

  const int gemm_blocks = (N + 15) / 16;

  // 1) y1 = x @ W1  -> bufA
  gemm_kernel<128, 16><<<gemm_blocks, 256, 0, stream>>>(x, W1, bufA, N);

  // 2) agg1 = scatter_add(y1) -> bufB
  hipMemsetAsync(bufB, 0, (size_t)N * NFEAT * sizeof(float), stream);
  {
    long long total = (long long)E * 128;
    int blocks = (int)((total + 255) / 256);
    scatter_add_kernel<128><<<blocks, 256, 0, stream>>>(bufA, src, dst, bufB, E);
  }

  // 3) h = relu(agg1 + b1) -> bufA
  {
    int n = N * NFEAT;
    relu_bias_kernel<<<(n + 255) / 256, 256, 0, stream>>>(bufB, b1, bufA, n);
  }

  // 4) y2 = h @ W2 -> bufB (N x 64)
  gemm_kernel<64, 16><<<gemm_blocks, 256, 0, stream>>>(bufA, W2, bufB, N);

  // 5) out = b2 + scatter_add(y2)
  {
    int n = N * 64;
    bias_init_kernel<<<(n + 255) / 256, 256, 0, stream>>>(b2, out, n);
    long long total = (long long)E * 64;
    int blocks = (int)((total + 255) / 256);
    scatter_add_kernel<64><<<blocks, 256, 0, stream>>>(bufB, src, dst, out, E);
  }
}

// Round 2
// 799.040 us; speedup vs baseline: 1.6686x; 1.6686x over previous
//
#include <hip/hip_runtime.h>
#include <hip/hip_bf16.h>

#define NFEAT 128

// ---------------------------------------------------------------------------
// GEMM: Y[nrows x COLS] = X[nrows x 128] @ W[128 x COLS]
// ---------------------------------------------------------------------------
template <int COLS, int RB>
__global__ __launch_bounds__(256) void gemm_kernel(
    const float* __restrict__ X, const float* __restrict__ W,
    float* __restrict__ Y, int nrows) {
  constexpr int G = 256 / COLS;   // row groups per block
  constexpr int RPT = RB / G;     // rows per thread
  __shared__ __align__(16) float Ws[128 * COLS];
  __shared__ __align__(16) float xs[RB][128];

  const int tid = threadIdx.x;
  const int row0 = blockIdx.x * RB;

  for (int i = tid * 4; i < 128 * COLS; i += 256 * 4) {
    *(float4*)&Ws[i] = *(const float4*)&W[i];
  }
  for (int i = tid * 4; i < RB * 128; i += 256 * 4) {
    int r = i >> 7, c = i & 127;
    int gr = row0 + r;
    float4 v = make_float4(0.f, 0.f, 0.f, 0.f);
    if (gr < nrows) v = *(const float4*)&X[(size_t)gr * 128 + c];
    *(float4*)&xs[r][c] = v;
  }
  __syncthreads();

  const int col = tid % COLS;
  const int rg = tid / COLS;

  float acc[RPT];
#pragma unroll
  for (int j = 0; j < RPT; j++) acc[j] = 0.f;

#pragma unroll 4
  for (int k = 0; k < 128; k += 4) {
    float w0 = Ws[(k + 0) * COLS + col];
    float w1 = Ws[(k + 1) * COLS + col];
    float w2 = Ws[(k + 2) * COLS + col];
    float w3 = Ws[(k + 3) * COLS + col];
#pragma unroll
    for (int j = 0; j < RPT; j++) {
      int r = rg + G * j;
      float4 xv = *(float4*)&xs[r][k];
      acc[j] += xv.x * w0 + xv.y * w1 + xv.z * w2 + xv.w * w3;
    }
  }

#pragma unroll
  for (int j = 0; j < RPT; j++) {
    int r = row0 + rg + G * j;
    if (r < nrows) Y[(size_t)r * COLS + col] = acc[j];
  }
}

// ---------------------------------------------------------------------------
// CSR build
// ---------------------------------------------------------------------------
__global__ __launch_bounds__(256) void hist_kernel(
    const int* __restrict__ dst, int* __restrict__ cnt, int E) {
  int e = blockIdx.x * 256 + threadIdx.x;
  if (e < E) atomicAdd(&cnt[dst[e]], 1);
}

// Single-block exclusive scan over N counts -> offsets[0..N]
__global__ __launch_bounds__(1024) void scan_kernel(
    const int* __restrict__ cnt, int* __restrict__ offsets, int N) {
  __shared__ int sums[1024];
  const int t = threadIdx.x;
  const int cpt = (N + 1023) / 1024;
  const int lo = t * cpt;
  const int hi = min(N, lo + cpt);
  int s = 0;
  for (int i = lo; i < hi; i++) s += cnt[i];
  sums[t] = s;
  __syncthreads();
  // Hillis-Steele inclusive scan
  for (int off = 1; off < 1024; off <<= 1) {
    int other = (t >= off) ? sums[t - off] : 0;
    __syncthreads();
    sums[t] += other;
    __syncthreads();
  }
  int run = (t > 0) ? sums[t - 1] : 0;
  for (int i = lo; i < hi; i++) { offsets[i] = run; run += cnt[i]; }
  if (t == 1023) offsets[N] = run;
}

// Fill csr_src, consuming cnt[] as a backward cursor (slot = off + (--cnt))
__global__ __launch_bounds__(256) void fill_kernel(
    const int* __restrict__ src, const int* __restrict__ dst,
    const int* __restrict__ offsets, int* __restrict__ cursor,
    int* __restrict__ csr_src, int E) {
  int e = blockIdx.x * 256 + threadIdx.x;
  if (e >= E) return;
  int d = dst[e];
  int p = atomicSub(&cursor[d], 1) - 1;
  csr_src[offsets[d] + p] = src[e];
}

// ---------------------------------------------------------------------------
// CSR aggregation: out[n] = (sum over edges into n of Y[src]) + bias, opt ReLU
// One wave (64 lanes) per node. C/64 channels per lane, contiguous -> coalesced.
// ---------------------------------------------------------------------------
template <int C, bool RELU>
__global__ __launch_bounds__(256) void csr_agg_kernel(
    const float* __restrict__ Y, const int* __restrict__ csr_src,
    const int* __restrict__ offsets, const float* __restrict__ bias,
    float* __restrict__ out, int N) {
  const int wave = (blockIdx.x * 256 + threadIdx.x) >> 6;
  const int lane = threadIdx.x & 63;
  if (wave >= N) return;
  const int start = offsets[wave];
  const int end = offsets[wave + 1];

  if constexpr (C == 128) {
    float2 acc = *(const float2*)&bias[2 * lane];
    for (int base = start; base < end; base += 64) {
      int my = (base + lane < end) ? csr_src[base + lane] : 0;
      int m = min(64, end - base);
      for (int j = 0; j < m; j++) {
        int s = __shfl(my, j);
        float2 v = *(const float2*)&Y[(size_t)s * 128 + 2 * lane];
        acc.x += v.x;
        acc.y += v.y;
      }
    }
    if (RELU) {
      acc.x = fmaxf(acc.x, 0.f);
      acc.y = fmaxf(acc.y, 0.f);
    }
    *(float2*)&out[(size_t)wave * 128 + 2 * lane] = acc;
  } else {
    float acc = bias[lane];
    for (int base = start; base < end; base += 64) {
      int my = (base + lane < end) ? csr_src[base + lane] : 0;
      int m = min(64, end - base);
      for (int j = 0; j < m; j++) {
        int s = __shfl(my, j);
        acc += Y[(size_t)s * C + lane];
      }
    }
    if (RELU) acc = fmaxf(acc, 0.f);
    out[(size_t)wave * C + lane] = acc;
  }
}

// ---------------------------------------------------------------------------
// Fallback (round-1 atomic path) kernels
// ---------------------------------------------------------------------------
template <int C>
__global__ __launch_bounds__(256) void scatter_add_kernel(
    const float* __restrict__ Y, const int* __restrict__ src,
    const int* __restrict__ dst, float* __restrict__ agg, int E) {
  int t = blockIdx.x * 256 + threadIdx.x;
  int e = t / C;
  int c = t % C;
  if (e >= E) return;
  atomicAdd(&agg[(size_t)dst[e] * C + c], Y[(size_t)src[e] * C + c]);
}

__global__ __launch_bounds__(256) void relu_bias_kernel(
    const float* __restrict__ agg, const float* __restrict__ b,
    float* __restrict__ h, int n) {
  int t = blockIdx.x * 256 + threadIdx.x;
  if (t >= n) return;
  float v = agg[t] + b[t & (NFEAT - 1)];
  h[t] = v > 0.f ? v : 0.f;
}

__global__ __launch_bounds__(256) void bias_init_kernel(
    const float* __restrict__ b, float* __restrict__ out, int n) {
  int t = blockIdx.x * 256 + threadIdx.x;
  if (t >= n) return;
  out[t] = b[t & 63];
}

extern "C" void kernel_launch(void* const* d_in, const int* in_sizes, int n_in,
                              void* d_out, int out_size, void* d_ws, size_t ws_size,
                              hipStream_t stream) {
  const float* x  = (const float*)d_in[0];
  const int* src  = (const int*)d_in[1];
  const int* dst  = (const int*)d_in[2];
  const float* W1 = (const float*)d_in[3];
  const float* b1 = (const float*)d_in[4];
  const float* W2 = (const float*)d_in[5];
  const float* b2 = (const float*)d_in[6];
  float* out = (float*)d_out;

  const int N = in_sizes[0] / NFEAT;   // 100000
  const int E = in_sizes[1];           // 1600000

  float* bufA = (float*)d_ws;                  // N*128 fp32 (y1, then y2)
  float* bufB = bufA + (size_t)N * NFEAT;      // N*128 fp32 (h)

  const size_t needed = (size_t)N * NFEAT * 2 * sizeof(float) +
                        ((size_t)2 * N + 1 + (size_t)E) * sizeof(int);

  const int gemm_blocks = (N + 15) / 16;
  const int edge_blocks = (E + 255) / 256;

  if (ws_size >= needed) {
    int* counts  = (int*)(bufB + (size_t)N * NFEAT);  // N
    int* offsets = counts + N;                        // N+1
    int* csr_src = offsets + N + 1;                   // E

    // ---- CSR build ----
    hipMemsetAsync(counts, 0, (size_t)N * sizeof(int), stream);
    hist_kernel<<<edge_blocks, 256, 0, stream>>>(dst, counts, E);
    scan_kernel<<<1, 1024, 0, stream>>>(counts, offsets, N);
    fill_kernel<<<edge_blocks, 256, 0, stream>>>(src, dst, offsets, counts,
                                                 csr_src, E);

    // ---- layer 1 ----
    gemm_kernel<128, 16><<<gemm_blocks, 256, 0, stream>>>(x, W1, bufA, N);
    {
      int blocks = (N * 64 + 255) / 256;  // one wave per node
      csr_agg_kernel<128, true><<<blocks, 256, 0, stream>>>(
          bufA, csr_src, offsets, b1, bufB, N);
    }

    // ---- layer 2 ----
    gemm_kernel<64, 16><<<gemm_blocks, 256, 0, stream>>>(bufB, W2, bufA, N);
    {
      int blocks = (N * 64 + 255) / 256;
      csr_agg_kernel<64, false><<<blocks, 256, 0, stream>>>(
          bufA, csr_src, offsets, b2, out, N);
    }
  } else {
    // ---- fallback: round-1 atomic path ----
    gemm_kernel<128, 16><<<gemm_blocks, 256, 0, stream>>>(x, W1, bufA, N);
    hipMemsetAsync(bufB, 0, (size_t)N * NFEAT * sizeof(float), stream);
    {
      long long total = (long long)E * 128;
      int blocks = (int)((total + 255) / 256);
      scatter_add_kernel<128><<<blocks, 256, 0, stream>>>(bufA, src, dst, bufB, E);
    }
    {
      int n = N * NFEAT;
      relu_bias_kernel<<<(n + 255) / 256, 256, 0, stream>>>(bufB, b1, bufA, n);
    }
    gemm_kernel<64, 16><<<gemm_blocks, 256, 0, stream>>>(bufA, W2, bufB, N);
    {
      int n = N * 64;
      bias_init_kernel<<<(n + 255) / 256, 256, 0, stream>>>(b2, out, n);
      long long total = (long long)E * 64;
      int blocks = (int)((total + 255) / 256);
      scatter_add_kernel<64><<<blocks, 256, 0, stream>>>(bufB, src, dst, out, E);
    }
  }
}

// Round 3
// 679.839 us; speedup vs baseline: 1.9611x; 1.1753x over previous
//
#include <hip/hip_runtime.h>
#include <hip/hip_bf16.h>

#define NFEAT 128

// ---------------------------------------------------------------------------
// GEMM: Y[nrows x COLS] = X[nrows x 128] @ W[128 x COLS]
// ---------------------------------------------------------------------------
template <int COLS, int RB>
__global__ __launch_bounds__(256) void gemm_kernel(
    const float* __restrict__ X, const float* __restrict__ W,
    float* __restrict__ Y, int nrows) {
  constexpr int G = 256 / COLS;   // row groups per block
  constexpr int RPT = RB / G;     // rows per thread
  __shared__ __align__(16) float Ws[128 * COLS];
  __shared__ __align__(16) float xs[RB][128];

  const int tid = threadIdx.x;
  const int row0 = blockIdx.x * RB;

  for (int i = tid * 4; i < 128 * COLS; i += 256 * 4) {
    *(float4*)&Ws[i] = *(const float4*)&W[i];
  }
  for (int i = tid * 4; i < RB * 128; i += 256 * 4) {
    int r = i >> 7, c = i & 127;
    int gr = row0 + r;
    float4 v = make_float4(0.f, 0.f, 0.f, 0.f);
    if (gr < nrows) v = *(const float4*)&X[(size_t)gr * 128 + c];
    *(float4*)&xs[r][c] = v;
  }
  __syncthreads();

  const int col = tid % COLS;
  const int rg = tid / COLS;

  float acc[RPT];
#pragma unroll
  for (int j = 0; j < RPT; j++) acc[j] = 0.f;

#pragma unroll 4
  for (int k = 0; k < 128; k += 4) {
    float w0 = Ws[(k + 0) * COLS + col];
    float w1 = Ws[(k + 1) * COLS + col];
    float w2 = Ws[(k + 2) * COLS + col];
    float w3 = Ws[(k + 3) * COLS + col];
#pragma unroll
    for (int j = 0; j < RPT; j++) {
      int r = rg + G * j;
      float4 xv = *(float4*)&xs[r][k];
      acc[j] += xv.x * w0 + xv.y * w1 + xv.z * w2 + xv.w * w3;
    }
  }

#pragma unroll
  for (int j = 0; j < RPT; j++) {
    int r = row0 + rg + G * j;
    if (r < nrows) Y[(size_t)r * COLS + col] = acc[j];
  }
}

// ---------------------------------------------------------------------------
// CSR build
// ---------------------------------------------------------------------------
__global__ __launch_bounds__(256) void hist_kernel(
    const int* __restrict__ dst, int* __restrict__ cnt, int E) {
  int e = blockIdx.x * 256 + threadIdx.x;
  if (e < E) atomicAdd(&cnt[dst[e]], 1);
}

// ---- device-wide exclusive scan, 3 phases, 1024 elems per block ----
#define SCAN_TILE 1024

// phase1: block b -> partials[b] = sum(cnt[b*1024 .. b*1024+1023])
__global__ __launch_bounds__(256) void scan_phase1(
    const int* __restrict__ cnt, int* __restrict__ partials, int N) {
  const int tid = threadIdx.x;
  const int base = blockIdx.x * SCAN_TILE + tid * 4;
  int s = 0;
  if (base + 3 < N) {
    int4 v = *(const int4*)&cnt[base];
    s = v.x + v.y + v.z + v.w;
  } else {
    for (int k = 0; k < 4; k++)
      if (base + k < N) s += cnt[base + k];
  }
  // wave reduce
  for (int off = 32; off > 0; off >>= 1) s += __shfl_down(s, off);
  __shared__ int ws[4];
  if ((tid & 63) == 0) ws[tid >> 6] = s;
  __syncthreads();
  if (tid == 0) partials[blockIdx.x] = ws[0] + ws[1] + ws[2] + ws[3];
}

// phase2: single small block, exclusive scan of nb partials (nb <= 1024)
__global__ __launch_bounds__(1024) void scan_phase2(
    int* __restrict__ partials, int nb) {
  __shared__ int sh[1024];
  const int t = threadIdx.x;
  sh[t] = (t < nb) ? partials[t] : 0;
  __syncthreads();
  for (int off = 1; off < 1024; off <<= 1) {
    int other = (t >= off) ? sh[t - off] : 0;
    __syncthreads();
    sh[t] += other;
    __syncthreads();
  }
  if (t < nb) partials[t] = (t > 0) ? sh[t - 1] : 0;  // exclusive
}

// phase3: block b writes offsets[b*1024 .. ) = partials[b] + local exclusive scan
__global__ __launch_bounds__(256) void scan_phase3(
    const int* __restrict__ cnt, const int* __restrict__ partials,
    int* __restrict__ offsets, int N, int E) {
  const int tid = threadIdx.x;
  const int base = blockIdx.x * SCAN_TILE + tid * 4;
  int v0 = 0, v1 = 0, v2 = 0, v3 = 0;
  if (base + 3 < N) {
    int4 v = *(const int4*)&cnt[base];
    v0 = v.x; v1 = v.y; v2 = v.z; v3 = v.w;
  } else {
    if (base + 0 < N) v0 = cnt[base + 0];
    if (base + 1 < N) v1 = cnt[base + 1];
    if (base + 2 < N) v2 = cnt[base + 2];
    if (base + 3 < N) v3 = cnt[base + 3];
  }
  int mysum = v0 + v1 + v2 + v3;
  __shared__ int sh[256];
  sh[tid] = mysum;
  __syncthreads();
  for (int off = 1; off < 256; off <<= 1) {
    int other = (tid >= off) ? sh[tid - off] : 0;
    __syncthreads();
    sh[tid] += other;
    __syncthreads();
  }
  int run = partials[blockIdx.x] + ((tid > 0) ? sh[tid - 1] : 0);
  if (base + 3 < N) {
    int4 o;
    o.x = run;
    o.y = run + v0;
    o.z = run + v0 + v1;
    o.w = run + v0 + v1 + v2;
    *(int4*)&offsets[base] = o;
  } else {
    int r = run;
    if (base + 0 < N) { offsets[base + 0] = r; r += v0; }
    if (base + 1 < N) { offsets[base + 1] = r; r += v1; }
    if (base + 2 < N) { offsets[base + 2] = r; r += v2; }
    if (base + 3 < N) { offsets[base + 3] = r; r += v3; }
  }
  if (blockIdx.x == 0 && tid == 0) offsets[N] = E;
}

// Fill csr_src, consuming cnt[] as a backward cursor (slot = off + (--cnt))
__global__ __launch_bounds__(256) void fill_kernel(
    const int* __restrict__ src, const int* __restrict__ dst,
    const int* __restrict__ offsets, int* __restrict__ cursor,
    int* __restrict__ csr_src, int E) {
  int e = blockIdx.x * 256 + threadIdx.x;
  if (e >= E) return;
  int d = dst[e];
  int p = atomicSub(&cursor[d], 1) - 1;
  csr_src[offsets[d] + p] = src[e];
}

// ---------------------------------------------------------------------------
// CSR aggregation: out[n] = (sum over edges into n of Y[src]) + bias, opt ReLU
// One wave (64 lanes) per node.
// ---------------------------------------------------------------------------
template <int C, bool RELU>
__global__ __launch_bounds__(256) void csr_agg_kernel(
    const float* __restrict__ Y, const int* __restrict__ csr_src,
    const int* __restrict__ offsets, const float* __restrict__ bias,
    float* __restrict__ out, int N) {
  const int wave = (blockIdx.x * 256 + threadIdx.x) >> 6;
  const int lane = threadIdx.x & 63;
  if (wave >= N) return;
  const int start = offsets[wave];
  const int end = offsets[wave + 1];

  if constexpr (C == 128) {
    float2 acc = *(const float2*)&bias[2 * lane];
    for (int base = start; base < end; base += 64) {
      int my = (base + lane < end) ? csr_src[base + lane] : 0;
      int m = min(64, end - base);
      for (int j = 0; j < m; j++) {
        int s = __shfl(my, j);
        float2 v = *(const float2*)&Y[(size_t)s * 128 + 2 * lane];
        acc.x += v.x;
        acc.y += v.y;
      }
    }
    if (RELU) {
      acc.x = fmaxf(acc.x, 0.f);
      acc.y = fmaxf(acc.y, 0.f);
    }
    *(float2*)&out[(size_t)wave * 128 + 2 * lane] = acc;
  } else {
    float acc = bias[lane];
    for (int base = start; base < end; base += 64) {
      int my = (base + lane < end) ? csr_src[base + lane] : 0;
      int m = min(64, end - base);
      for (int j = 0; j < m; j++) {
        int s = __shfl(my, j);
        acc += Y[(size_t)s * C + lane];
      }
    }
    if (RELU) acc = fmaxf(acc, 0.f);
    out[(size_t)wave * C + lane] = acc;
  }
}

extern "C" void kernel_launch(void* const* d_in, const int* in_sizes, int n_in,
                              void* d_out, int out_size, void* d_ws, size_t ws_size,
                              hipStream_t stream) {
  const float* x  = (const float*)d_in[0];
  const int* src  = (const int*)d_in[1];
  const int* dst  = (const int*)d_in[2];
  const float* W1 = (const float*)d_in[3];
  const float* b1 = (const float*)d_in[4];
  const float* W2 = (const float*)d_in[5];
  const float* b2 = (const float*)d_in[6];
  float* out = (float*)d_out;

  const int N = in_sizes[0] / NFEAT;   // 100000
  const int E = in_sizes[1];           // 1600000

  float* bufA = (float*)d_ws;                  // N*128 fp32 (y1, then y2)
  float* bufB = bufA + (size_t)N * NFEAT;      // N*128 fp32 (h)

  int* counts  = (int*)(bufB + (size_t)N * NFEAT);  // N
  int* offsets = counts + N;                        // N+1
  int* csr_src = offsets + N + 1;                   // E
  int* partials = csr_src + E;                      // <=1024

  const int gemm_blocks = (N + 15) / 16;
  const int edge_blocks = (E + 255) / 256;
  const int scan_blocks = (N + SCAN_TILE - 1) / SCAN_TILE;

  // ---- CSR build ----
  hipMemsetAsync(counts, 0, (size_t)N * sizeof(int), stream);
  hist_kernel<<<edge_blocks, 256, 0, stream>>>(dst, counts, E);
  scan_phase1<<<scan_blocks, 256, 0, stream>>>(counts, partials, N);
  scan_phase2<<<1, 1024, 0, stream>>>(partials, scan_blocks);
  scan_phase3<<<scan_blocks, 256, 0, stream>>>(counts, partials, offsets, N, E);
  fill_kernel<<<edge_blocks, 256, 0, stream>>>(src, dst, offsets, counts,
                                               csr_src, E);

  // ---- layer 1 ----
  gemm_kernel<128, 16><<<gemm_blocks, 256, 0, stream>>>(x, W1, bufA, N);
  {
    int blocks = (N * 64 + 255) / 256;  // one wave per node
    csr_agg_kernel<128, true><<<blocks, 256, 0, stream>>>(
        bufA, csr_src, offsets, b1, bufB, N);
  }

  // ---- layer 2 ----
  gemm_kernel<64, 16><<<gemm_blocks, 256, 0, stream>>>(bufB, W2, bufA, N);
  {
    int blocks = (N * 64 + 255) / 256;
    csr_agg_kernel<64, false><<<blocks, 256, 0, stream>>>(
        bufA, csr_src, offsets, b2, out, N);
  }
}

// Round 4
// 508.087 us; speedup vs baseline: 2.6240x; 1.3380x over previous
//
#include <hip/hip_runtime.h>
#include <hip/hip_bf16.h>

#define NFEAT 128

typedef __attribute__((ext_vector_type(8))) short short8;
typedef __attribute__((ext_vector_type(4))) float float4v;

__device__ inline short f32_bf16(float f) {
  unsigned u = __builtin_bit_cast(unsigned, f);
  unsigned r = (u + 0x7fffu + ((u >> 16) & 1u)) >> 16;
  return (short)r;
}
__device__ inline float bf16_f32(unsigned short s) {
  return __builtin_bit_cast(float, (unsigned)s << 16);
}

// ---------------------------------------------------------------------------
// Repack W (fp32, KxCOLS row-major) into B-fragment order for
// mfma_f32_16x16x32_bf16: frag f = ((t*4 + c)*64 + lane), 8 bf16 per frag:
//   Wf[f*8 + j] = bf16( W[(c*32 + (lane>>4)*8 + j) * COLS + t*16 + (lane&15)] )
// block 0 -> W1 (COLS=128), block 1 -> W2 (COLS=64)
// ---------------------------------------------------------------------------
__device__ inline void repack_one(const float* __restrict__ W,
                                  short* __restrict__ Wf, int COLS) {
  int nfrag = (COLS / 16) * 4 * 64;
  for (int f = threadIdx.x; f < nfrag; f += 256) {
    int lane = f & 63, c = (f >> 6) & 3, t = f >> 8;
    int k0 = c * 32 + (lane >> 4) * 8;
    int n = t * 16 + (lane & 15);
    short8 v;
#pragma unroll
    for (int j = 0; j < 8; j++) v[j] = f32_bf16(W[(size_t)(k0 + j) * COLS + n]);
    *(short8*)&Wf[(size_t)f * 8] = v;
  }
}
__global__ __launch_bounds__(256) void repack_w_kernel(
    const float* __restrict__ W1, short* __restrict__ W1f,
    const float* __restrict__ W2, short* __restrict__ W2f) {
  if (blockIdx.x == 0) repack_one(W1, W1f, 128);
  else repack_one(W2, W2f, 64);
}

// ---------------------------------------------------------------------------
// MFMA GEMM: Y_bf16[nrows x COLS] = A[nrows x 128] @ W[128 x COLS]
// A is fp32 (IN_BF16=false, converted on load) or bf16. Wf is frag-ordered.
// Block = 256 threads = 4 waves; 64 rows/block (16 rows/wave).
// ---------------------------------------------------------------------------
template <int COLS, bool IN_BF16>
__global__ __launch_bounds__(256) void gemm_mfma(
    const void* __restrict__ Av, const short* __restrict__ Wf,
    short* __restrict__ Y, int nrows) {
  constexpr int NT = COLS / 16;
  __shared__ __align__(16) short lds[COLS * 128];

  // stage frag-ordered W into LDS (COLS*128*2 bytes)
  {
    const int4* s = (const int4*)Wf;
    int4* d = (int4*)lds;
    for (int i = threadIdx.x; i < COLS * 16; i += 256) d[i] = s[i];
  }
  __syncthreads();

  const int wave = threadIdx.x >> 6;
  const int lane = threadIdx.x & 63;
  const int m = lane & 15;
  const int q = lane >> 4;
  const int rowA = blockIdx.x * 64 + wave * 16 + m;

  float4v acc[NT];
#pragma unroll
  for (int t = 0; t < NT; t++) acc[t] = (float4v){0.f, 0.f, 0.f, 0.f};

  const short8* ldsf = (const short8*)lds;
#pragma unroll
  for (int c = 0; c < 4; c++) {
    short8 a = (short8){0, 0, 0, 0, 0, 0, 0, 0};
    if (rowA < nrows) {
      if constexpr (IN_BF16) {
        a = *(const short8*)((const short*)Av + (size_t)rowA * 128 + c * 32 + q * 8);
      } else {
        const float* xp = (const float*)Av + (size_t)rowA * 128 + c * 32 + q * 8;
        float4 x0 = *(const float4*)xp;
        float4 x1 = *(const float4*)(xp + 4);
        a[0] = f32_bf16(x0.x); a[1] = f32_bf16(x0.y);
        a[2] = f32_bf16(x0.z); a[3] = f32_bf16(x0.w);
        a[4] = f32_bf16(x1.x); a[5] = f32_bf16(x1.y);
        a[6] = f32_bf16(x1.z); a[7] = f32_bf16(x1.w);
      }
    }
#pragma unroll
    for (int t = 0; t < NT; t++) {
      acc[t] = __builtin_amdgcn_mfma_f32_16x16x32_bf16(
          a, ldsf[(t * 4 + c) * 64 + lane], acc[t], 0, 0, 0);
    }
  }

  // C/D layout: col = lane&15 (=m), row = q*4 + reg
  const int rbase = blockIdx.x * 64 + wave * 16 + q * 4;
#pragma unroll
  for (int t = 0; t < NT; t++) {
#pragma unroll
    for (int r = 0; r < 4; r++) {
      int rr = rbase + r;
      if (rr < nrows) Y[(size_t)rr * COLS + t * 16 + m] = f32_bf16(acc[t][r]);
    }
  }
}

// ---------------------------------------------------------------------------
// CSR build
// ---------------------------------------------------------------------------
__global__ __launch_bounds__(256) void hist_kernel(
    const int* __restrict__ dst, int* __restrict__ cnt, int E) {
  int e = blockIdx.x * 256 + threadIdx.x;
  if (e < E) atomicAdd(&cnt[dst[e]], 1);
}

#define SCAN_TILE 1024

__global__ __launch_bounds__(256) void scan_phase1(
    const int* __restrict__ cnt, int* __restrict__ partials, int N) {
  const int tid = threadIdx.x;
  const int base = blockIdx.x * SCAN_TILE + tid * 4;
  int s = 0;
  if (base + 3 < N) {
    int4 v = *(const int4*)&cnt[base];
    s = v.x + v.y + v.z + v.w;
  } else {
    for (int k = 0; k < 4; k++)
      if (base + k < N) s += cnt[base + k];
  }
  for (int off = 32; off > 0; off >>= 1) s += __shfl_down(s, off);
  __shared__ int ws[4];
  if ((tid & 63) == 0) ws[tid >> 6] = s;
  __syncthreads();
  if (tid == 0) partials[blockIdx.x] = ws[0] + ws[1] + ws[2] + ws[3];
}

__global__ __launch_bounds__(1024) void scan_phase2(
    int* __restrict__ partials, int nb) {
  __shared__ int sh[1024];
  const int t = threadIdx.x;
  sh[t] = (t < nb) ? partials[t] : 0;
  __syncthreads();
  for (int off = 1; off < 1024; off <<= 1) {
    int other = (t >= off) ? sh[t - off] : 0;
    __syncthreads();
    sh[t] += other;
    __syncthreads();
  }
  if (t < nb) partials[t] = (t > 0) ? sh[t - 1] : 0;
}

__global__ __launch_bounds__(256) void scan_phase3(
    const int* __restrict__ cnt, const int* __restrict__ partials,
    int* __restrict__ offsets, int N, int E) {
  const int tid = threadIdx.x;
  const int base = blockIdx.x * SCAN_TILE + tid * 4;
  int v0 = 0, v1 = 0, v2 = 0, v3 = 0;
  if (base + 3 < N) {
    int4 v = *(const int4*)&cnt[base];
    v0 = v.x; v1 = v.y; v2 = v.z; v3 = v.w;
  } else {
    if (base + 0 < N) v0 = cnt[base + 0];
    if (base + 1 < N) v1 = cnt[base + 1];
    if (base + 2 < N) v2 = cnt[base + 2];
    if (base + 3 < N) v3 = cnt[base + 3];
  }
  int mysum = v0 + v1 + v2 + v3;
  __shared__ int sh[256];
  sh[tid] = mysum;
  __syncthreads();
  for (int off = 1; off < 256; off <<= 1) {
    int other = (tid >= off) ? sh[tid - off] : 0;
    __syncthreads();
    sh[tid] += other;
    __syncthreads();
  }
  int run = partials[blockIdx.x] + ((tid > 0) ? sh[tid - 1] : 0);
  if (base + 3 < N) {
    int4 o;
    o.x = run;
    o.y = run + v0;
    o.z = run + v0 + v1;
    o.w = run + v0 + v1 + v2;
    *(int4*)&offsets[base] = o;
  } else {
    int r = run;
    if (base + 0 < N) { offsets[base + 0] = r; r += v0; }
    if (base + 1 < N) { offsets[base + 1] = r; r += v1; }
    if (base + 2 < N) { offsets[base + 2] = r; r += v2; }
    if (base + 3 < N) { offsets[base + 3] = r; r += v3; }
  }
  if (blockIdx.x == 0 && tid == 0) offsets[N] = E;
}

__global__ __launch_bounds__(256) void fill_kernel(
    const int* __restrict__ src, const int* __restrict__ dst,
    const int* __restrict__ offsets, int* __restrict__ cursor,
    int* __restrict__ csr_src, int E) {
  int e = blockIdx.x * 256 + threadIdx.x;
  if (e >= E) return;
  int d = dst[e];
  int p = atomicSub(&cursor[d], 1) - 1;
  csr_src[offsets[d] + p] = src[e];
}

// ---------------------------------------------------------------------------
// Aggregations (one wave per node, fp32 accumulate)
// ---------------------------------------------------------------------------
// layer 1: in y1 bf16 [N x 128], out h bf16, bias fp32, ReLU
__global__ __launch_bounds__(256) void agg1_kernel(
    const short* __restrict__ Y, const int* __restrict__ csr_src,
    const int* __restrict__ offsets, const float* __restrict__ bias,
    short* __restrict__ H, int N) {
  const int node = (blockIdx.x * 256 + threadIdx.x) >> 6;
  const int lane = threadIdx.x & 63;
  if (node >= N) return;
  const int start = offsets[node];
  const int end = offsets[node + 1];
  float a0 = bias[2 * lane], a1 = bias[2 * lane + 1];
  for (int base = start; base < end; base += 64) {
    int my = (base + lane < end) ? csr_src[base + lane] : 0;
    int mcnt = min(64, end - base);
    for (int j = 0; j < mcnt; j++) {
      int s = __shfl(my, j);
      unsigned v = *(const unsigned*)&Y[(size_t)s * 128 + 2 * lane];
      a0 += __builtin_bit_cast(float, v << 16);
      a1 += __builtin_bit_cast(float, v & 0xffff0000u);
    }
  }
  a0 = fmaxf(a0, 0.f);
  a1 = fmaxf(a1, 0.f);
  unsigned outv = (unsigned)(unsigned short)f32_bf16(a0) |
                  ((unsigned)(unsigned short)f32_bf16(a1) << 16);
  *(unsigned*)&H[(size_t)node * 128 + 2 * lane] = outv;
}

// layer 2: in y2 bf16 [N x 64], out fp32 + b2, no ReLU
__global__ __launch_bounds__(256) void agg2_kernel(
    const short* __restrict__ Y, const int* __restrict__ csr_src,
    const int* __restrict__ offsets, const float* __restrict__ bias,
    float* __restrict__ out, int N) {
  const int node = (blockIdx.x * 256 + threadIdx.x) >> 6;
  const int lane = threadIdx.x & 63;
  if (node >= N) return;
  const int start = offsets[node];
  const int end = offsets[node + 1];
  float acc = bias[lane];
  for (int base = start; base < end; base += 64) {
    int my = (base + lane < end) ? csr_src[base + lane] : 0;
    int mcnt = min(64, end - base);
    for (int j = 0; j < mcnt; j++) {
      int s = __shfl(my, j);
      acc += bf16_f32(*(const unsigned short*)&Y[(size_t)s * 64 + lane]);
    }
  }
  out[(size_t)node * 64 + lane] = acc;
}

extern "C" void kernel_launch(void* const* d_in, const int* in_sizes, int n_in,
                              void* d_out, int out_size, void* d_ws, size_t ws_size,
                              hipStream_t stream) {
  const float* x  = (const float*)d_in[0];
  const int* src  = (const int*)d_in[1];
  const int* dst  = (const int*)d_in[2];
  const float* W1 = (const float*)d_in[3];
  const float* b1 = (const float*)d_in[4];
  const float* W2 = (const float*)d_in[5];
  const float* b2 = (const float*)d_in[6];
  float* out = (float*)d_out;

  const int N = in_sizes[0] / NFEAT;   // 100000
  const int E = in_sizes[1];           // 1600000

  // workspace layout
  short* y1  = (short*)d_ws;                       // N*128 bf16
  short* h   = y1 + (size_t)N * 128;               // N*128 bf16
  short* y2  = h + (size_t)N * 128;                // N*64 bf16
  short* w1f = y2 + (size_t)N * 64;                // 128*128 bf16
  short* w2f = w1f + 128 * 128;                    // 128*64 bf16
  int* counts = (int*)(((uintptr_t)(w2f + 128 * 64) + 15) & ~(uintptr_t)15);
  int* offsets  = counts + N;                      // N+1
  int* csr_src  = offsets + N + 1;                 // E
  int* partials = csr_src + E;                     // <=1024

  const int edge_blocks = (E + 255) / 256;
  const int scan_blocks = (N + SCAN_TILE - 1) / SCAN_TILE;
  const int gemm_blocks = (N + 63) / 64;
  const int agg_blocks = (N * 64 + 255) / 256;

  // ---- weight repack (independent of everything else) ----
  repack_w_kernel<<<2, 256, 0, stream>>>(W1, w1f, W2, w2f);

  // ---- CSR build ----
  hipMemsetAsync(counts, 0, (size_t)N * sizeof(int), stream);
  hist_kernel<<<edge_blocks, 256, 0, stream>>>(dst, counts, E);
  scan_phase1<<<scan_blocks, 256, 0, stream>>>(counts, partials, N);
  scan_phase2<<<1, 1024, 0, stream>>>(partials, scan_blocks);
  scan_phase3<<<scan_blocks, 256, 0, stream>>>(counts, partials, offsets, N, E);
  fill_kernel<<<edge_blocks, 256, 0, stream>>>(src, dst, offsets, counts,
                                               csr_src, E);

  // ---- layer 1 ----
  gemm_mfma<128, false><<<gemm_blocks, 256, 0, stream>>>(x, w1f, y1, N);
  agg1_kernel<<<agg_blocks, 256, 0, stream>>>(y1, csr_src, offsets, b1, h, N);

  // ---- layer 2 ----
  gemm_mfma<64, true><<<gemm_blocks, 256, 0, stream>>>(h, w2f, y2, N);
  agg2_kernel<<<agg_blocks, 256, 0, stream>>>(y2, csr_src, offsets, b2, out, N);
}

// Round 5
// 378.801 us; speedup vs baseline: 3.5196x; 1.3413x over previous
//
#include <hip/hip_runtime.h>
#include <hip/hip_bf16.h>

#define NFEAT 128

typedef __attribute__((ext_vector_type(8))) short short8;
typedef __attribute__((ext_vector_type(4))) float float4v;

__device__ inline short f32_bf16(float f) {
  unsigned u = __builtin_bit_cast(unsigned, f);
  unsigned r = (u + 0x7fffu + ((u >> 16) & 1u)) >> 16;
  return (short)r;
}
__device__ inline float bf16_f32(unsigned short s) {
  return __builtin_bit_cast(float, (unsigned)s << 16);
}

// ---------------------------------------------------------------------------
// Repack W (fp32, KxCOLS row-major) into B-fragment order for
// mfma_f32_16x16x32_bf16.
// ---------------------------------------------------------------------------
__device__ inline void repack_one(const float* __restrict__ W,
                                  short* __restrict__ Wf, int COLS) {
  int nfrag = (COLS / 16) * 4 * 64;
  for (int f = threadIdx.x; f < nfrag; f += 256) {
    int lane = f & 63, c = (f >> 6) & 3, t = f >> 8;
    int k0 = c * 32 + (lane >> 4) * 8;
    int n = t * 16 + (lane & 15);
    short8 v;
#pragma unroll
    for (int j = 0; j < 8; j++) v[j] = f32_bf16(W[(size_t)(k0 + j) * COLS + n]);
    *(short8*)&Wf[(size_t)f * 8] = v;
  }
}
__global__ __launch_bounds__(256) void repack_w_kernel(
    const float* __restrict__ W1, short* __restrict__ W1f,
    const float* __restrict__ W2, short* __restrict__ W2f) {
  if (blockIdx.x == 0) repack_one(W1, W1f, 128);
  else repack_one(W2, W2f, 64);
}

// ---------------------------------------------------------------------------
// MFMA GEMM: Y_bf16[nrows x COLS] = A[nrows x 128] @ W[128 x COLS]
// ---------------------------------------------------------------------------
template <int COLS, bool IN_BF16>
__global__ __launch_bounds__(256) void gemm_mfma(
    const void* __restrict__ Av, const short* __restrict__ Wf,
    short* __restrict__ Y, int nrows) {
  constexpr int NT = COLS / 16;
  __shared__ __align__(16) short lds[COLS * 128];

  {
    const int4* s = (const int4*)Wf;
    int4* d = (int4*)lds;
    for (int i = threadIdx.x; i < COLS * 16; i += 256) d[i] = s[i];
  }
  __syncthreads();

  const int wave = threadIdx.x >> 6;
  const int lane = threadIdx.x & 63;
  const int m = lane & 15;
  const int q = lane >> 4;
  const int rowA = blockIdx.x * 64 + wave * 16 + m;

  float4v acc[NT];
#pragma unroll
  for (int t = 0; t < NT; t++) acc[t] = (float4v){0.f, 0.f, 0.f, 0.f};

  const short8* ldsf = (const short8*)lds;
#pragma unroll
  for (int c = 0; c < 4; c++) {
    short8 a = (short8){0, 0, 0, 0, 0, 0, 0, 0};
    if (rowA < nrows) {
      if constexpr (IN_BF16) {
        a = *(const short8*)((const short*)Av + (size_t)rowA * 128 + c * 32 + q * 8);
      } else {
        const float* xp = (const float*)Av + (size_t)rowA * 128 + c * 32 + q * 8;
        float4 x0 = *(const float4*)xp;
        float4 x1 = *(const float4*)(xp + 4);
        a[0] = f32_bf16(x0.x); a[1] = f32_bf16(x0.y);
        a[2] = f32_bf16(x0.z); a[3] = f32_bf16(x0.w);
        a[4] = f32_bf16(x1.x); a[5] = f32_bf16(x1.y);
        a[6] = f32_bf16(x1.z); a[7] = f32_bf16(x1.w);
      }
    }
#pragma unroll
    for (int t = 0; t < NT; t++) {
      acc[t] = __builtin_amdgcn_mfma_f32_16x16x32_bf16(
          a, ldsf[(t * 4 + c) * 64 + lane], acc[t], 0, 0, 0);
    }
  }

  const int rbase = blockIdx.x * 64 + wave * 16 + q * 4;
#pragma unroll
  for (int t = 0; t < NT; t++) {
#pragma unroll
    for (int r = 0; r < 4; r++) {
      int rr = rbase + r;
      if (rr < nrows) Y[(size_t)rr * COLS + t * 16 + m] = f32_bf16(acc[t][r]);
    }
  }
}

// ---------------------------------------------------------------------------
// CSR build
// ---------------------------------------------------------------------------
__global__ __launch_bounds__(256) void hist_kernel(
    const int* __restrict__ dst, int* __restrict__ cnt, int E) {
  int e = blockIdx.x * 256 + threadIdx.x;
  if (e < E) atomicAdd(&cnt[dst[e]], 1);
}

#define SCAN_TILE 1024

__global__ __launch_bounds__(256) void scan_phase1(
    const int* __restrict__ cnt, int* __restrict__ partials, int N) {
  const int tid = threadIdx.x;
  const int base = blockIdx.x * SCAN_TILE + tid * 4;
  int s = 0;
  if (base + 3 < N) {
    int4 v = *(const int4*)&cnt[base];
    s = v.x + v.y + v.z + v.w;
  } else {
    for (int k = 0; k < 4; k++)
      if (base + k < N) s += cnt[base + k];
  }
  for (int off = 32; off > 0; off >>= 1) s += __shfl_down(s, off);
  __shared__ int ws[4];
  if ((tid & 63) == 0) ws[tid >> 6] = s;
  __syncthreads();
  if (tid == 0) partials[blockIdx.x] = ws[0] + ws[1] + ws[2] + ws[3];
}

__global__ __launch_bounds__(1024) void scan_phase2(
    int* __restrict__ partials, int nb) {
  __shared__ int sh[1024];
  const int t = threadIdx.x;
  sh[t] = (t < nb) ? partials[t] : 0;
  __syncthreads();
  for (int off = 1; off < 1024; off <<= 1) {
    int other = (t >= off) ? sh[t - off] : 0;
    __syncthreads();
    sh[t] += other;
    __syncthreads();
  }
  if (t < nb) partials[t] = (t > 0) ? sh[t - 1] : 0;
}

__global__ __launch_bounds__(256) void scan_phase3(
    const int* __restrict__ cnt, const int* __restrict__ partials,
    int* __restrict__ offsets, int N, int E) {
  const int tid = threadIdx.x;
  const int base = blockIdx.x * SCAN_TILE + tid * 4;
  int v0 = 0, v1 = 0, v2 = 0, v3 = 0;
  if (base + 3 < N) {
    int4 v = *(const int4*)&cnt[base];
    v0 = v.x; v1 = v.y; v2 = v.z; v3 = v.w;
  } else {
    if (base + 0 < N) v0 = cnt[base + 0];
    if (base + 1 < N) v1 = cnt[base + 1];
    if (base + 2 < N) v2 = cnt[base + 2];
    if (base + 3 < N) v3 = cnt[base + 3];
  }
  int mysum = v0 + v1 + v2 + v3;
  __shared__ int sh[256];
  sh[tid] = mysum;
  __syncthreads();
  for (int off = 1; off < 256; off <<= 1) {
    int other = (tid >= off) ? sh[tid - off] : 0;
    __syncthreads();
    sh[tid] += other;
    __syncthreads();
  }
  int run = partials[blockIdx.x] + ((tid > 0) ? sh[tid - 1] : 0);
  if (base + 3 < N) {
    int4 o;
    o.x = run;
    o.y = run + v0;
    o.z = run + v0 + v1;
    o.w = run + v0 + v1 + v2;
    *(int4*)&offsets[base] = o;
  } else {
    int r = run;
    if (base + 0 < N) { offsets[base + 0] = r; r += v0; }
    if (base + 1 < N) { offsets[base + 1] = r; r += v1; }
    if (base + 2 < N) { offsets[base + 2] = r; r += v2; }
    if (base + 3 < N) { offsets[base + 3] = r; r += v3; }
  }
  if (blockIdx.x == 0 && tid == 0) offsets[N] = E;
}

// ---------------------------------------------------------------------------
// Windowed fill: block group (blockIdx&7) only commits edges whose dst falls
// in its 1/8 node window -> scattered writes stay in an ~800 KB L2-resident
// region (and blockIdx&7 round-robins onto XCDs, so a line is dirtied by one
// XCD and evicted full). Correctness independent of XCD mapping.
// ---------------------------------------------------------------------------
__global__ __launch_bounds__(256) void fill_win_kernel(
    const int* __restrict__ src, const int* __restrict__ dst,
    const int* __restrict__ offsets, int* __restrict__ cursor,
    int* __restrict__ csr_src, int E, int win_size) {
  const int w = blockIdx.x & 7;
  const int blk = blockIdx.x >> 3;
  const int nblk = gridDim.x >> 3;
  const int lo = w * win_size;
  const int hi = lo + win_size;
  for (int e = blk * 256 + threadIdx.x; e < E; e += nblk * 256) {
    int d = dst[e];
    if (d >= lo && d < hi) {
      int p = atomicSub(&cursor[d], 1) - 1;
      csr_src[offsets[d] + p] = src[e];
    }
  }
}

// ---------------------------------------------------------------------------
// Aggregations (one wave per node, fp32 accumulate, 4-way unrolled gather)
// ---------------------------------------------------------------------------
__global__ __launch_bounds__(256) void agg1_kernel(
    const short* __restrict__ Y, const int* __restrict__ csr_src,
    const int* __restrict__ offsets, const float* __restrict__ bias,
    short* __restrict__ H, int N) {
  const int node = (blockIdx.x * 256 + threadIdx.x) >> 6;
  const int lane = threadIdx.x & 63;
  if (node >= N) return;
  const int start = offsets[node];
  const int end = offsets[node + 1];
  float a0 = bias[2 * lane], a1 = bias[2 * lane + 1];
  for (int base = start; base < end; base += 64) {
    int my = (base + lane < end) ? csr_src[base + lane] : 0;
    int mcnt = min(64, end - base);
    int j = 0;
    for (; j + 4 <= mcnt; j += 4) {
      int s0 = __shfl(my, j + 0);
      int s1 = __shfl(my, j + 1);
      int s2 = __shfl(my, j + 2);
      int s3 = __shfl(my, j + 3);
      unsigned v0 = *(const unsigned*)&Y[(size_t)s0 * 128 + 2 * lane];
      unsigned v1 = *(const unsigned*)&Y[(size_t)s1 * 128 + 2 * lane];
      unsigned v2 = *(const unsigned*)&Y[(size_t)s2 * 128 + 2 * lane];
      unsigned v3 = *(const unsigned*)&Y[(size_t)s3 * 128 + 2 * lane];
      a0 += __builtin_bit_cast(float, v0 << 16);
      a1 += __builtin_bit_cast(float, v0 & 0xffff0000u);
      a0 += __builtin_bit_cast(float, v1 << 16);
      a1 += __builtin_bit_cast(float, v1 & 0xffff0000u);
      a0 += __builtin_bit_cast(float, v2 << 16);
      a1 += __builtin_bit_cast(float, v2 & 0xffff0000u);
      a0 += __builtin_bit_cast(float, v3 << 16);
      a1 += __builtin_bit_cast(float, v3 & 0xffff0000u);
    }
    for (; j < mcnt; j++) {
      int s = __shfl(my, j);
      unsigned v = *(const unsigned*)&Y[(size_t)s * 128 + 2 * lane];
      a0 += __builtin_bit_cast(float, v << 16);
      a1 += __builtin_bit_cast(float, v & 0xffff0000u);
    }
  }
  a0 = fmaxf(a0, 0.f);
  a1 = fmaxf(a1, 0.f);
  unsigned outv = (unsigned)(unsigned short)f32_bf16(a0) |
                  ((unsigned)(unsigned short)f32_bf16(a1) << 16);
  *(unsigned*)&H[(size_t)node * 128 + 2 * lane] = outv;
}

__global__ __launch_bounds__(256) void agg2_kernel(
    const short* __restrict__ Y, const int* __restrict__ csr_src,
    const int* __restrict__ offsets, const float* __restrict__ bias,
    float* __restrict__ out, int N) {
  const int node = (blockIdx.x * 256 + threadIdx.x) >> 6;
  const int lane = threadIdx.x & 63;
  if (node >= N) return;
  const int start = offsets[node];
  const int end = offsets[node + 1];
  float acc = bias[lane];
  for (int base = start; base < end; base += 64) {
    int my = (base + lane < end) ? csr_src[base + lane] : 0;
    int mcnt = min(64, end - base);
    int j = 0;
    for (; j + 4 <= mcnt; j += 4) {
      int s0 = __shfl(my, j + 0);
      int s1 = __shfl(my, j + 1);
      int s2 = __shfl(my, j + 2);
      int s3 = __shfl(my, j + 3);
      unsigned short w0 = *(const unsigned short*)&Y[(size_t)s0 * 64 + lane];
      unsigned short w1 = *(const unsigned short*)&Y[(size_t)s1 * 64 + lane];
      unsigned short w2 = *(const unsigned short*)&Y[(size_t)s2 * 64 + lane];
      unsigned short w3 = *(const unsigned short*)&Y[(size_t)s3 * 64 + lane];
      acc += bf16_f32(w0) + bf16_f32(w1) + bf16_f32(w2) + bf16_f32(w3);
    }
    for (; j < mcnt; j++) {
      int s = __shfl(my, j);
      acc += bf16_f32(*(const unsigned short*)&Y[(size_t)s * 64 + lane]);
    }
  }
  out[(size_t)node * 64 + lane] = acc;
}

extern "C" void kernel_launch(void* const* d_in, const int* in_sizes, int n_in,
                              void* d_out, int out_size, void* d_ws, size_t ws_size,
                              hipStream_t stream) {
  const float* x  = (const float*)d_in[0];
  const int* src  = (const int*)d_in[1];
  const int* dst  = (const int*)d_in[2];
  const float* W1 = (const float*)d_in[3];
  const float* b1 = (const float*)d_in[4];
  const float* W2 = (const float*)d_in[5];
  const float* b2 = (const float*)d_in[6];
  float* out = (float*)d_out;

  const int N = in_sizes[0] / NFEAT;   // 100000
  const int E = in_sizes[1];           // 1600000

  // workspace layout
  short* y1  = (short*)d_ws;                       // N*128 bf16
  short* h   = y1 + (size_t)N * 128;               // N*128 bf16
  short* y2  = h + (size_t)N * 128;                // N*64 bf16
  short* w1f = y2 + (size_t)N * 64;                // 128*128 bf16
  short* w2f = w1f + 128 * 128;                    // 128*64 bf16
  int* counts = (int*)(((uintptr_t)(w2f + 128 * 64) + 15) & ~(uintptr_t)15);
  int* offsets  = counts + N;                      // N+1
  int* csr_src  = offsets + N + 1;                 // E
  int* partials = csr_src + E;                     // <=1024

  const int edge_blocks = (E + 255) / 256;
  const int scan_blocks = (N + SCAN_TILE - 1) / SCAN_TILE;
  const int gemm_blocks = (N + 63) / 64;
  const int agg_blocks = (N * 64 + 255) / 256;
  const int win_size = (N + 7) / 8;

  // ---- weight repack ----
  repack_w_kernel<<<2, 256, 0, stream>>>(W1, w1f, W2, w2f);

  // ---- CSR build ----
  hipMemsetAsync(counts, 0, (size_t)N * sizeof(int), stream);
  hist_kernel<<<edge_blocks, 256, 0, stream>>>(dst, counts, E);
  scan_phase1<<<scan_blocks, 256, 0, stream>>>(counts, partials, N);
  scan_phase2<<<1, 1024, 0, stream>>>(partials, scan_blocks);
  scan_phase3<<<scan_blocks, 256, 0, stream>>>(counts, partials, offsets, N, E);
  fill_win_kernel<<<2048, 256, 0, stream>>>(src, dst, offsets, counts,
                                            csr_src, E, win_size);

  // ---- layer 1 ----
  gemm_mfma<128, false><<<gemm_blocks, 256, 0, stream>>>(x, w1f, y1, N);
  agg1_kernel<<<agg_blocks, 256, 0, stream>>>(y1, csr_src, offsets, b1, h, N);

  // ---- layer 2 ----
  gemm_mfma<64, true><<<gemm_blocks, 256, 0, stream>>>(h, w2f, y2, N);
  agg2_kernel<<<agg_blocks, 256, 0, stream>>>(y2, csr_src, offsets, b2, out, N);
}